// Round 13
// baseline (258.712 us; speedup 1.0000x reference)
//
#include <hip/hip_runtime.h>

#define NB 16
#define DMODEL 4096
#define NH 32
#define NKV 8
#define HD 128
#define SEQ 4096
#define PASTN 4095
#define EQKV 6144           // 4096 q + 1024 k + 1024 v rows
#define NCHUNK 16
#define CHUNKS 256          // rows per chunk-block (SEQ/NCHUNK)
#define PSTRIDE 136         // partials stride (16B aligned)
#define SCALE 0.08838834764831845f  // 1/sqrt(128)

typedef float v4f __attribute__((ext_vector_type(4)));

// ---------------- Kernel 1: QKV projection, double-buffered staging --------
__global__ __launch_bounds__(256) void qkv_proj(
    const float* __restrict__ hs, const float* __restrict__ Wq,
    const float* __restrict__ Wk, const float* __restrict__ Wv,
    float* __restrict__ raw /* [B][6144] */) {
  __shared__ __align__(16) float ld[2][16][256];   // 32 KB
  __shared__ __align__(16) float red[4][32][33];   // 16.9 KB
  const int tid = threadIdx.x, wid = tid >> 6, lane = tid & 63;
  const int e0 = blockIdx.x * 8 + wid * 2;
  const int fo = lane * 4;

  const float* wrow[2];
#pragma unroll
  for (int r = 0; r < 2; ++r) {
    int e = e0 + r;
    wrow[r] = (e < 4096) ? (Wq + (size_t)e * DMODEL)
            : (e < 5120) ? (Wk + (size_t)(e - 4096) * DMODEL)
                         : (Wv + (size_t)(e - 5120) * DMODEL);
  }

  float acc[2][16];
#pragma unroll
  for (int r = 0; r < 2; ++r)
#pragma unroll
    for (int b = 0; b < 16; ++b) acc[r][b] = 0.f;

  v4f st[4];
#pragma unroll
  for (int i = 0; i < 4; ++i)
    st[i] = *(const v4f*)(hs + (size_t)(i * 4 + wid) * DMODEL + fo);
#pragma unroll
  for (int i = 0; i < 4; ++i)
    *(v4f*)(&ld[0][i * 4 + wid][fo]) = st[i];
  v4f w4[2];
#pragma unroll
  for (int r = 0; r < 2; ++r) w4[r] = *(const v4f*)(wrow[r] + fo);
  __syncthreads();

  for (int c = 0; c < 16; ++c) {
    const int k1 = (c + 1) * 256;
    v4f w4n[2];
    if (c < 15) {
#pragma unroll
      for (int i = 0; i < 4; ++i)
        st[i] = *(const v4f*)(hs + (size_t)(i * 4 + wid) * DMODEL + k1 + fo);
#pragma unroll
      for (int r = 0; r < 2; ++r) w4n[r] = *(const v4f*)(wrow[r] + k1 + fo);
    }
    const float* lb = &ld[c & 1][0][0];
#pragma unroll
    for (int b = 0; b < 16; ++b) {
      v4f h4 = *(const v4f*)(lb + b * 256 + fo);
#pragma unroll
      for (int r = 0; r < 2; ++r) {
        v4f t = w4[r] * h4;
        acc[r][b] += t[0] + t[1] + t[2] + t[3];
      }
    }
    if (c < 15) {
#pragma unroll
      for (int i = 0; i < 4; ++i)
        *(v4f*)(&ld[(c + 1) & 1][i * 4 + wid][fo]) = st[i];
      w4[0] = w4n[0];
      w4[1] = w4n[1];
    }
    __syncthreads();
  }

#pragma unroll
  for (int r = 0; r < 2; ++r)
#pragma unroll
    for (int b = 0; b < 16; ++b) acc[r][b] += __shfl_xor(acc[r][b], 32);

  if (lane < 32) {
#pragma unroll
    for (int r = 0; r < 2; ++r)
#pragma unroll
      for (int b = 0; b < 16; ++b)
        red[wid][lane][r * 16 + b] = acc[r][b];
  }
  __syncthreads();
  if (lane < 32) {
    float s = 0.f;
#pragma unroll
    for (int t2 = 0; t2 < 32; ++t2) s += red[wid][t2][lane];
    const int r = lane >> 4, bb = lane & 15;
    raw[(size_t)bb * EQKV + e0 + r] = s;
  }
}

// ---------------- Kernel 2: phase-split flash-decode + fused RoPE ----------
// grid (16,8,16) = 2048 blocks; 4 waves/block; wave owns 64 rows.
// Q-rope computed in-block from raw. Row 4095 (new K/V) is computed, written
// and consumed by the single block that owns it (chunk 15, wid 3).
__global__ __launch_bounds__(256, 4) void attn_decode(
    const float* __restrict__ pastK, const float* __restrict__ pastV,
    const float* __restrict__ raw, const void* __restrict__ pos_ids,
    const float* __restrict__ mask,
    float* __restrict__ kc, float* __restrict__ vc,
    float* __restrict__ part /* [B][32][NCHUNK][PSTRIDE] */) {
  __shared__ __align__(16) float sm[4][4][132];  // [wave][head][m,l,pad,ctx128]

  const int chunk = blockIdx.x, kv = blockIdx.y, b = blockIdx.z;
  const int tid = threadIdx.x, wid = tid >> 6, lane = tid & 63;
  const int half = lane >> 5, q32 = lane & 31;
  const int fo = q32 * 4;          // float offset within the lane's row

  // ---- RoPE angles for this lane's 4 dims (shared by q and k rows) ----
  const int* pi = (const int*)pos_ids;
  long long pos = (pi[1] == 0 && pi[0] != 0) ? ((const long long*)pos_ids)[b]
                                             : (long long)pi[b];
  const float fpos = (float)pos;
  float sn[4], cs[4];
#pragma unroll
  for (int j = 0; j < 4; ++j) {
    int i = (fo & 63) + j;
    float inv_freq = powf(10000.f, -(float)(2 * i) * (1.f / 128.f));
    sincosf(fpos * inv_freq, &sn[j], &cs[j]);
  }

  // ---- Q: rope 4 heads of this kv group from raw ----
  const float* rb = raw + (size_t)b * EQKV;
  v4f q[4];
#pragma unroll
  for (int h = 0; h < 4; ++h) {
    const float* src = rb + (kv * 4 + h) * HD;
    v4f x = *(const v4f*)(src + fo);
    v4f y = *(const v4f*)(src + (fo ^ 64));
#pragma unroll
    for (int j = 0; j < 4; ++j) {
      float rot = (fo < 64) ? -y[j] : y[j];
      q[h][j] = x[j] * cs[j] + rot * sn[j];
    }
  }

  const size_t prow = ((size_t)b * NKV + kv) * PASTN;
  const size_t crow = ((size_t)b * NKV + kv) * SEQ;
  const int base = chunk * CHUNKS + wid * (CHUNKS / 4);
  const float* mrow = mask + (size_t)b * SEQ;

  // ---- special block owns row 4095: rope k_new, copy v_new, write caches --
  const bool special = (chunk == NCHUNK - 1) && (wid == 3);
  v4f knew4 = {0.f, 0.f, 0.f, 0.f}, vnew4 = {0.f, 0.f, 0.f, 0.f};
  if (special) {
    const float* ks = rb + 4096 + kv * HD;
    v4f x = *(const v4f*)(ks + fo);
    v4f y = *(const v4f*)(ks + (fo ^ 64));
#pragma unroll
    for (int j = 0; j < 4; ++j) {
      float rot = (fo < 64) ? -y[j] : y[j];
      knew4[j] = x[j] * cs[j] + rot * sn[j];
    }
    vnew4 = *(const v4f*)(rb + 5120 + kv * HD + fo);
    if (half == 0) {
      *(v4f*)(kc + (crow + PASTN) * HD + fo) = knew4;
      *(v4f*)(vc + (crow + PASTN) * HD + fo) = vnew4;
    }
  }

  // mask preload: lane L holds mask[base + 2*(L&31) + (L>>5)];
  // step t's value for this lane sits at source lane t | (lane & 32).
  const float mreg = mrow[base + 2 * q32 + half];

  // keep[h]: score of row (2*q32 + half) for head h (filled in phase 1)
  float keep[4];

  // =================== Phase 1: K stream + scores ===================
  {
    v4f kq[4];
#pragma unroll
    for (int i = 0; i < 4; ++i) {
      const int s = base + 2 * i + half;
      v4f tmp = knew4;
      if (s < PASTN)
        tmp = __builtin_nontemporal_load((const v4f*)(pastK + (prow + s) * HD + fo));
      kq[i] = tmp;
    }

#pragma unroll 4
    for (int t = 0; t < 32; ++t) {
      const int sp = base + 2 * t;
      const int s = sp + half;
      const v4f kch = kq[t & 3];
      if (t < 28) {
        const int s2 = sp + 8 + half;
        v4f tmp = knew4;
        if (s2 < PASTN)
          tmp = __builtin_nontemporal_load((const v4f*)(pastK + (prow + s2) * HD + fo));
        kq[t & 3] = tmp;
      }
      if (s < PASTN)
        __builtin_nontemporal_store(kch, (v4f*)(kc + (crow + s) * HD + fo));

      const float mval = __shfl(mreg, t | (lane & 32));

      float d4[4];
#pragma unroll
      for (int h = 0; h < 4; ++h) {
        v4f tv = q[h] * kch;
        d4[h] = tv[0] + tv[1] + tv[2] + tv[3];
      }
#pragma unroll
      for (int off = 1; off <= 16; off <<= 1)
#pragma unroll
        for (int h = 0; h < 4; ++h) d4[h] += __shfl_xor(d4[h], off);

#pragma unroll
      for (int h = 0; h < 4; ++h) {
        float sc = d4[h] * SCALE + mval;
        if (q32 == t) keep[h] = sc;   // row 2t+half kept by lane t|(half<<5)
      }
    }
  }

  // =================== Phase 2: true max, V stream ===================
  float m[4], l[4];
  v4f c[4];
#pragma unroll
  for (int h = 0; h < 4; ++h) {
    float mm = keep[h];
#pragma unroll
    for (int off = 1; off <= 32; off <<= 1)
      mm = fmaxf(mm, __shfl_xor(mm, off));
    m[h] = mm;                        // true max over all 64 rows
    l[h] = 0.f;
    c[h] = (v4f){0.f, 0.f, 0.f, 0.f};
  }

  {
    v4f vq[4];
#pragma unroll
    for (int i = 0; i < 4; ++i) {
      const int s = base + 2 * i + half;
      v4f tmp = vnew4;
      if (s < PASTN)
        tmp = __builtin_nontemporal_load((const v4f*)(pastV + (prow + s) * HD + fo));
      vq[i] = tmp;
    }

#pragma unroll 4
    for (int t = 0; t < 32; ++t) {
      const int sp = base + 2 * t;
      const int s = sp + half;
      const v4f vch = vq[t & 3];
      if (t < 28) {
        const int s2 = sp + 8 + half;
        v4f tmp = vnew4;
        if (s2 < PASTN)
          tmp = __builtin_nontemporal_load((const v4f*)(pastV + (prow + s2) * HD + fo));
        vq[t & 3] = tmp;
      }
      if (s < PASTN)
        __builtin_nontemporal_store(vch, (v4f*)(vc + (crow + s) * HD + fo));

#pragma unroll
      for (int h = 0; h < 4; ++h) {
        float p = __expf(__shfl(keep[h], t | (lane & 32)) - m[h]);
        l[h] += p;
        c[h] += p * vch;
      }
    }
  }

  // merge the two half-streams (same m — plain add, no rescale)
#pragma unroll
  for (int h = 0; h < 4; ++h) {
    l[h] += __shfl_xor(l[h], 32);
#pragma unroll
    for (int j = 0; j < 4; ++j) c[h][j] += __shfl_xor(c[h][j], 32);
  }

  if (half == 0) {
#pragma unroll
    for (int h = 0; h < 4; ++h) {
      if (q32 == 0) { sm[wid][h][0] = m[h]; sm[wid][h][1] = l[h]; }
      *(v4f*)(&sm[wid][h][4 + fo]) = c[h];
    }
  }
  __syncthreads();

  // wave `wid` merges head `wid` across the 4 wave-slices
  float mstar = -1e30f;
#pragma unroll
  for (int sl = 0; sl < 4; ++sl) mstar = fmaxf(mstar, sm[sl][wid][0]);
  float den = 0.f;
  const int d2 = lane * 2;
  float nx = 0.f, ny = 0.f;
#pragma unroll
  for (int sl = 0; sl < 4; ++sl) {
    float w = __expf(sm[sl][wid][0] - mstar);
    den += w * sm[sl][wid][1];
    nx += w * sm[sl][wid][4 + d2];
    ny += w * sm[sl][wid][4 + d2 + 1];
  }
  float* pp = part + (((size_t)b * NH + kv * 4 + wid) * NCHUNK + chunk) * PSTRIDE;
  if (lane == 0) { pp[0] = mstar; pp[1] = den; }
  float2 nv = {nx, ny};
  *(float2*)(pp + 4 + d2) = nv;
}

// ---------------- Kernel 3: combine chunk partials ------------------------
__global__ void combine(const float* __restrict__ part, float* __restrict__ ctx) {
  const int bh = blockIdx.x;        // 0..511
  const int lane = threadIdx.x;     // 64
  const float* pp = part + (size_t)bh * NCHUNK * PSTRIDE;
  float mstar = -1e30f;
#pragma unroll
  for (int c = 0; c < NCHUNK; ++c) mstar = fmaxf(mstar, pp[c * PSTRIDE]);
  float den = 0.f, nx = 0.f, ny = 0.f;
  const int d2 = lane * 2;
#pragma unroll
  for (int c = 0; c < NCHUNK; ++c) {
    float w = __expf(pp[c * PSTRIDE] - mstar);
    den += w * pp[c * PSTRIDE + 1];
    float2 pv = *(const float2*)(pp + c * PSTRIDE + 4 + d2);
    nx += w * pv.x;
    ny += w * pv.y;
  }
  float inv = 1.0f / den;
  ctx[(size_t)bh * HD + d2] = nx * inv;
  ctx[(size_t)bh * HD + d2 + 1] = ny * inv;
}

// ---------------- Kernel 4: output projection, double-buffered staging -----
__global__ __launch_bounds__(256) void out_proj(
    const float* __restrict__ ctx, const float* __restrict__ Wo,
    float* __restrict__ out) {
  __shared__ __align__(16) float ld[2][16][256];   // 32 KB
  __shared__ __align__(16) float red[4][32][33];   // 16.9 KB
  const int tid = threadIdx.x, wid = tid >> 6, lane = tid & 63;
  const int e0 = blockIdx.x * 8 + wid * 2;
  const int fo = lane * 4;

  float acc[2][16];
#pragma unroll
  for (int r = 0; r < 2; ++r)
#pragma unroll
    for (int b = 0; b < 16; ++b) acc[r][b] = 0.f;

  v4f st[4];
#pragma unroll
  for (int i = 0; i < 4; ++i)
    st[i] = *(const v4f*)(ctx + (size_t)(i * 4 + wid) * DMODEL + fo);
#pragma unroll
  for (int i = 0; i < 4; ++i)
    *(v4f*)(&ld[0][i * 4 + wid][fo]) = st[i];
  v4f w4[2];
#pragma unroll
  for (int r = 0; r < 2; ++r)
    w4[r] = *(const v4f*)(Wo + (size_t)(e0 + r) * DMODEL + fo);
  __syncthreads();

  for (int c = 0; c < 16; ++c) {
    const int k1 = (c + 1) * 256;
    v4f w4n[2];
    if (c < 15) {
#pragma unroll
      for (int i = 0; i < 4; ++i)
        st[i] = *(const v4f*)(ctx + (size_t)(i * 4 + wid) * DMODEL + k1 + fo);
#pragma unroll
      for (int r = 0; r < 2; ++r)
        w4n[r] = *(const v4f*)(Wo + (size_t)(e0 + r) * DMODEL + k1 + fo);
    }
    const float* lb = &ld[c & 1][0][0];
#pragma unroll
    for (int b = 0; b < 16; ++b) {
      v4f h4 = *(const v4f*)(lb + b * 256 + fo);
#pragma unroll
      for (int r = 0; r < 2; ++r) {
        v4f t = w4[r] * h4;
        acc[r][b] += t[0] + t[1] + t[2] + t[3];
      }
    }
    if (c < 15) {
#pragma unroll
      for (int i = 0; i < 4; ++i)
        *(v4f*)(&ld[(c + 1) & 1][i * 4 + wid][fo]) = st[i];
      w4[0] = w4n[0];
      w4[1] = w4n[1];
    }
    __syncthreads();
  }

#pragma unroll
  for (int r = 0; r < 2; ++r)
#pragma unroll
    for (int b = 0; b < 16; ++b) acc[r][b] += __shfl_xor(acc[r][b], 32);

  if (lane < 32) {
#pragma unroll
    for (int r = 0; r < 2; ++r)
#pragma unroll
      for (int b = 0; b < 16; ++b)
        red[wid][lane][r * 16 + b] = acc[r][b];
  }
  __syncthreads();
  if (lane < 32) {
    float s = 0.f;
#pragma unroll
    for (int t2 = 0; t2 < 32; ++t2) s += red[wid][t2][lane];
    const int r = lane >> 4, bb = lane & 15;
    out[(size_t)bb * DMODEL + e0 + r] = s;
  }
}

// ---------------------------------------------------------------------------
extern "C" void kernel_launch(void* const* d_in, const int* in_sizes, int n_in,
                              void* d_out, int out_size, void* d_ws, size_t ws_size,
                              hipStream_t stream) {
  const float* hs    = (const float*)d_in[0];
  const float* mask  = (const float*)d_in[1];
  const void*  pos   = d_in[2];
  const float* pastK = (const float*)d_in[3];
  const float* pastV = (const float*)d_in[4];
  const float* Wq    = (const float*)d_in[5];
  const float* Wk    = (const float*)d_in[6];
  const float* Wv    = (const float*)d_in[7];
  const float* Wo    = (const float*)d_in[8];

  float* out  = (float*)d_out;
  float* attn = out;                                        // 16*4096
  float* kc   = out + (size_t)NB * DMODEL;                  // 16*8*4096*128
  float* vc   = kc + (size_t)NB * NKV * SEQ * HD;

  float* ws      = (float*)d_ws;
  float* ws_raw  = ws;                                         // 16*6144
  float* ws_part = ws_raw + (size_t)NB * EQKV;                 // 16*32*16*136
  float* ws_ctx  = ws_part + (size_t)NB * NH * NCHUNK * PSTRIDE; // 65536

  qkv_proj<<<EQKV / 8, 256, 0, stream>>>(hs, Wq, Wk, Wv, ws_raw);
  attn_decode<<<dim3(NCHUNK, NKV, NB), 256, 0, stream>>>(pastK, pastV, ws_raw, pos,
                                                         mask, kc, vc, ws_part);
  combine<<<NB * NH, 64, 0, stream>>>(ws_part, ws_ctx);
  out_proj<<<DMODEL / 8, 256, 0, stream>>>(ws_ctx, Wo, attn);
}